// Round 1
// baseline (42.116 us; speedup 1.0000x reference)
//
#include <hip/hip_runtime.h>

#define NT 128

__device__ __forceinline__ void st4(float* dst, float4 v) {
    dst[0] = v.x; dst[1] = v.y; dst[2] = v.z; dst[3] = v.w;
}
__device__ __forceinline__ float4 ld4(const float* s) {
    return make_float4(s[0], s[1], s[2], s[3]);
}

// acc += X @ Y   (8x8)
__device__ __forceinline__ void mm_add(float (&acc)[64], const float (&X)[64], const float (&Y)[64]) {
#pragma unroll
    for (int i = 0; i < 8; ++i) {
#pragma unroll
        for (int k = 0; k < 8; ++k) {
            const float x = X[i * 8 + k];
#pragma unroll
            for (int j = 0; j < 8; ++j)
                acc[i * 8 + j] = fmaf(x, Y[k * 8 + j], acc[i * 8 + j]);
        }
    }
}
// acc -= X @ Y   (8x8)
__device__ __forceinline__ void mm_sub(float (&acc)[64], const float (&X)[64], const float (&Y)[64]) {
#pragma unroll
    for (int i = 0; i < 8; ++i) {
#pragma unroll
        for (int k = 0; k < 8; ++k) {
            const float x = -X[i * 8 + k];
#pragma unroll
            for (int j = 0; j < 8; ++j)
                acc[i * 8 + j] = fmaf(x, Y[k * 8 + j], acc[i * 8 + j]);
        }
    }
}

__global__ __launch_bounds__(NT, 2)
void magnus6_kernel(const float* __restrict__ A,
                    const float* __restrict__ hp,
                    const float* __restrict__ y0,
                    float* __restrict__ out,
                    int B)
{
    // Per-thread-private spill space: column tx of each [chunk][NT] slab.
    // No cross-thread sharing -> no __syncthreads() anywhere.
    __shared__ float4 lds[2][16][NT];   // 64 KB

    const int tx  = threadIdx.x;
    const int tid = blockIdx.x * NT + tx;
    if (tid >= B) return;

    const float h    = hp[0];
    const float c_a2 = h * 1.2909944487358056f;   // h*sqrt(15)/3
    const float c_a3 = h * (10.0f / 3.0f);
    const float c_m  = 20.0f / 3.0f;

    const float4* __restrict__ Ap =
        reinterpret_cast<const float4*>(A + (size_t)tid * 192);

    float a1[64];   // alpha1, later Omega0 -> Omega
    float a2[64];   // A1 -> alpha2 -> [a1,T]-acc -> Q
    float t[64];    // C1-acc -> T -> P' = P/240

    // ---- load A1 -> a2 ----
#pragma unroll
    for (int c = 0; c < 16; ++c) st4(&a2[4 * c], Ap[c]);
    // ---- load A2, a1 = h*A2 ----
#pragma unroll
    for (int c = 0; c < 16; ++c) {
        float4 v = Ap[16 + c];
        a1[4 * c + 0] = h * v.x; a1[4 * c + 1] = h * v.y;
        a1[4 * c + 2] = h * v.z; a1[4 * c + 3] = h * v.w;
    }
    // ---- stream A3: alpha3 -> LDS slot0 ; alpha2 overwrites A1 in a2 ----
#pragma unroll
    for (int c = 0; c < 16; ++c) {
        float4 v = Ap[32 + c];
        float vv[4]; st4(vv, v);
        float w[4];
#pragma unroll
        for (int j = 0; j < 4; ++j) {
            const int idx = 4 * c + j;
            const float A1e = a2[idx];
            const float A3e = vv[j];
            w[j]   = c_a3 * (A1e + A3e) - c_m * a1[idx];  // alpha3 = h*10/3*(A1-2A2+A3)
            a2[idx] = c_a2 * (A3e - A1e);                 // alpha2
        }
        lds[0][c][tx] = ld4(w);
    }

    // ---- C1 = [alpha1, alpha2] into t ----
#pragma unroll
    for (int i = 0; i < 64; ++i) t[i] = 0.0f;
    mm_add(t, a1, a2);
    mm_sub(t, a2, a1);

    // ---- T = 2*alpha3 + C1 (in place) ----
#pragma unroll
    for (int c = 0; c < 16; ++c) {
        float vv[4]; st4(vv, lds[0][c][tx]);
#pragma unroll
        for (int j = 0; j < 4; ++j) t[4 * c + j] += 2.0f * vv[j];
    }

    // ---- spill alpha2 -> LDS slot1, reuse a2 as accumulator ----
#pragma unroll
    for (int c = 0; c < 16; ++c) lds[1][c][tx] = ld4(&a2[4 * c]);

    // ---- acc2 = [alpha1, T] into a2 ----
#pragma unroll
    for (int i = 0; i < 64; ++i) a2[i] = 0.0f;
    mm_add(a2, a1, t);
    mm_sub(a2, t, a1);

    // ---- Q = alpha2 + C2 = alpha2 - acc2/60 ----
#pragma unroll
    for (int c = 0; c < 16; ++c) {
        float vv[4]; st4(vv, lds[1][c][tx]);
#pragma unroll
        for (int j = 0; j < 4; ++j) {
            const int idx = 4 * c + j;
            a2[idx] = vv[j] - (1.0f / 60.0f) * a2[idx];
        }
    }

    // ---- P' = (T - 20*alpha1 - 3*alpha3)/240 (in t); Omega0 = alpha1 + alpha3/12 (in a1) ----
#pragma unroll
    for (int c = 0; c < 16; ++c) {
        float vv[4]; st4(vv, lds[0][c][tx]);
#pragma unroll
        for (int j = 0; j < 4; ++j) {
            const int idx = 4 * c + j;
            const float a3e = vv[j];
            t[idx]  = (1.0f / 240.0f) * (t[idx] - 20.0f * a1[idx] - 3.0f * a3e);
            a1[idx] = a1[idx] + (1.0f / 12.0f) * a3e;
        }
    }

    // ---- Omega = Omega0 + P'@Q - Q@P'  (accumulate into a1) ----
    mm_add(a1, t, a2);
    mm_sub(a1, a2, t);

    // ---- y = expm(Omega) @ y0 via Taylor matvecs (order 6) ----
    const float4* __restrict__ y0p =
        reinterpret_cast<const float4*>(y0 + (size_t)tid * 8);
    float v[8], y[8];
    st4(&v[0], y0p[0]); st4(&v[4], y0p[1]);
#pragma unroll
    for (int i = 0; i < 8; ++i) y[i] = v[i];

    const float inv[6] = {1.0f, 0.5f, 1.0f / 3.0f, 0.25f, 0.2f, 1.0f / 6.0f};
#pragma unroll
    for (int k = 0; k < 6; ++k) {
        float w[8];
#pragma unroll
        for (int i = 0; i < 8; ++i) {
            float s = 0.0f;
#pragma unroll
            for (int j = 0; j < 8; ++j) s = fmaf(a1[i * 8 + j], v[j], s);
            w[i] = s * inv[k];
        }
#pragma unroll
        for (int i = 0; i < 8; ++i) { v[i] = w[i]; y[i] += v[i]; }
    }

    float4* __restrict__ op = reinterpret_cast<float4*>(out + (size_t)tid * 8);
    op[0] = make_float4(y[0], y[1], y[2], y[3]);
    op[1] = make_float4(y[4], y[5], y[6], y[7]);
}

extern "C" void kernel_launch(void* const* d_in, const int* in_sizes, int n_in,
                              void* d_out, int out_size, void* d_ws, size_t ws_size,
                              hipStream_t stream)
{
    const float* A  = (const float*)d_in[0];
    const float* hp = (const float*)d_in[1];
    const float* y0 = (const float*)d_in[2];
    float* out = (float*)d_out;

    const int B = in_sizes[2] / 8;   // y0 is (B, 8)
    const int grid = (B + NT - 1) / NT;
    magnus6_kernel<<<grid, NT, 0, stream>>>(A, hp, y0, out, B);
}